// Round 19
// baseline (301.717 us; speedup 1.0000x reference)
//
#include <hip/hip_runtime.h>
#include <stdint.h>

typedef unsigned short u16;
typedef __attribute__((ext_vector_type(8))) short short8x;   // 8 x bf16 (4 VGPRs)
typedef __attribute__((ext_vector_type(4))) float floatx4;   // MFMA C/D
typedef __attribute__((ext_vector_type(4))) float f32x4;
typedef __attribute__((ext_vector_type(2))) unsigned int u32x2;

#define TOKENS 2048   // B*T
#define EMBED  4096
#define QKVN   6144   // 4096 q + 1024 k + 1024 v
#define T_SEQ  1024
#define SMAX   2048   // cache length (2*KV_SEQ_LEN)
#define NQH    32
#define NKVH   8
#define HD     128

// RNE f32 -> bf16 (finite inputs only)
static __device__ __forceinline__ u16 f2b(float f) {
    union { float f; uint32_t u; } v; v.f = f;
    uint32_t r = v.u + 0x7fffu + ((v.u >> 16) & 1u);
    return (u16)(r >> 16);
}
static __device__ __forceinline__ float b2f(u16 h) {
    union { uint32_t u; float f; } v; v.u = ((uint32_t)h) << 16; return v.f;
}

static __device__ __forceinline__ void gload_lds16(const u16* g, u16* l) {
    __builtin_amdgcn_global_load_lds(
        (const __attribute__((address_space(1))) uint32_t*)g,
        (__attribute__((address_space(3))) uint32_t*)l, 16, 0, 0);
}

// ---------------- fused f32 -> bf16 conversion: x, Wq, Wk, Wv ----------------
// R18: Wo conversion moved into attn's companion blocks (overlaps attn's
// latency-bound tail). This kernel now converts 192 MB instead of 288 MB.
#define CSEG0 2097152              // x        (2048*4096/4)
#define CSEG1 6291456              // +Wq      (4096*4096/4)
#define CSEG2 7340032              // +Wk      (1024*4096/4)
#define CSEG3 8388608              // +Wv      (1024*4096/4)
__global__ void convert_all_kernel(const float* __restrict__ x,  const float* __restrict__ Wq,
                                   const float* __restrict__ Wk, const float* __restrict__ Wv,
                                   u16* __restrict__ xb, u16* __restrict__ wqkv) {
    int i = blockIdx.x * blockDim.x + threadIdx.x;   // float4 index
    if (i >= CSEG3) return;
    const float4* src; uint2* dst; int off;
    if (i < CSEG0)      { src = (const float4*)x;  dst = (uint2*)xb;   off = i; }
    else if (i < CSEG1) { src = (const float4*)Wq; dst = (uint2*)wqkv; off = i - CSEG0; }
    else if (i < CSEG2) { src = (const float4*)Wk; dst = (uint2*)wqkv + 4194304; off = i - CSEG1; }
    else                { src = (const float4*)Wv; dst = (uint2*)wqkv + 5242880; off = i - CSEG2; }
    float4 f = src[off];
    union { u16 h[4]; uint2 v; } o;
    o.h[0] = f2b(f.x); o.h[1] = f2b(f.y); o.h[2] = f2b(f.z); o.h[3] = f2b(f.w);
    dst[off] = o.v;
}

#define FENCE asm volatile("" ::: "memory")
#define WAITZ asm volatile("s_waitcnt vmcnt(0)" ::: "memory")
#define NOSTG ((void)0)
#define NOW   ((void)0)

// ---------------- GEMM1: C[M,N] = A[M,K] * B[N,K]^T, 256x192 tile ----------------
// R10 schedule (107 us, MfmaUtil 42%). Full-machine grid (32x8). 8 waves (2M x 4N),
// per-wave 128x48, BK=64, ONE phase/K-tile. Default dispatch (R16 swizzle hurt
// here: B-panel sharing moved cross-XCD, FETCH 95->210MB).
#define HBA(BUF, H) (lds + (BUF) * 28672 + (H) * 8192)
#define HBB(BUF)    (lds + (BUF) * 28672 + 16384)
#define STGA(BUF, H, KT) do { \
    gload_lds16(gA[H][0] + (size_t)(KT) * 64, HBA(BUF, H) + dOffW); \
    gload_lds16(gA[H][1] + (size_t)(KT) * 64, HBA(BUF, H) + 4096 + dOffW); \
} while (0)
#define STGB(BUF, KT) do { \
    _Pragma("unroll") \
    for (int _L = 0; _L < 3; _L++) \
        gload_lds16(gBv[_L] + (size_t)(KT) * 64, HBB(BUF) + _L * 4096 + dOffW); \
} while (0)
#define STGALL(BUF, KT) do { STGA(BUF, 0, KT); STGA(BUF, 1, KT); STGB(BUF, KT); } while (0)
#define PH1(CBUF, STAGES, ENDW) do { \
    const u16* _pa0 = HBA(CBUF, 0); \
    const u16* _pa1 = HBA(CBUF, 1); \
    const u16* _pb  = HBB(CBUF); \
    short8x af0[4][2], af1[4][2], bf[3][2]; \
    _Pragma("unroll") \
    for (int _mi = 0; _mi < 4; _mi++) { \
        af0[_mi][0] = *(const short8x*)(_pa0 + offA[_mi][0]); \
        af0[_mi][1] = *(const short8x*)(_pa0 + offA[_mi][1]); } \
    _Pragma("unroll") \
    for (int _nj = 0; _nj < 3; _nj++) { \
        bf[_nj][0] = *(const short8x*)(_pb + offB[_nj][0]); \
        bf[_nj][1] = *(const short8x*)(_pb + offB[_nj][1]); } \
    STAGES; \
    __builtin_amdgcn_sched_barrier(0); \
    _Pragma("unroll") \
    for (int _mi = 0; _mi < 4; _mi++) { \
        af1[_mi][0] = *(const short8x*)(_pa1 + offA[_mi][0]); \
        af1[_mi][1] = *(const short8x*)(_pa1 + offA[_mi][1]); } \
    __builtin_amdgcn_s_setprio(1); \
    _Pragma("unroll") \
    for (int _kk = 0; _kk < 2; _kk++) \
        _Pragma("unroll") \
        for (int _mi = 0; _mi < 4; _mi++) \
            _Pragma("unroll") \
            for (int _nj = 0; _nj < 3; _nj++) \
                acc[0][_mi][_nj] = __builtin_amdgcn_mfma_f32_16x16x32_bf16( \
                    af0[_mi][_kk], bf[_nj][_kk], acc[0][_mi][_nj], 0, 0, 0); \
    _Pragma("unroll") \
    for (int _kk = 0; _kk < 2; _kk++) \
        _Pragma("unroll") \
        for (int _mi = 0; _mi < 4; _mi++) \
            _Pragma("unroll") \
            for (int _nj = 0; _nj < 3; _nj++) \
                acc[1][_mi][_nj] = __builtin_amdgcn_mfma_f32_16x16x32_bf16( \
                    af1[_mi][_kk], bf[_nj][_kk], acc[1][_mi][_nj], 0, 0, 0); \
    __builtin_amdgcn_s_setprio(0); \
    ENDW; \
    FENCE; __builtin_amdgcn_s_barrier(); FENCE; \
} while (0)

__global__ __launch_bounds__(512, 1) void gemm256_kernel(
    const u16* __restrict__ A, const u16* __restrict__ Bw,
    u16* __restrict__ Cv, int N, int K) {
    extern __shared__ __align__(16) u16 lds[];   // 112 KiB dynamic
    const int tid = threadIdx.x;
    const int lane = tid & 63, w = tid >> 6;
    const int quad = lane >> 4, lc = lane & 15;
    const int wm = w >> 2, wn = w & 3;           // 2M x 4N wave grid
    const int Mbase = blockIdx.y * 256, Nbase = blockIdx.x * 192;

    const int r8 = lane >> 3;                    // row within 8-row wave stripe
    const int sl = (lane & 7) ^ r8;              // pre-swizzled 16B slot in row
    const int srow = w * 8 + r8;                 // 0..63 within a 64-row load unit
    const u16* gA[2][2];                         // [half][unit]
    const u16* gBv[3];
#pragma unroll
    for (int H = 0; H < 2; H++)
#pragma unroll
        for (int L = 0; L < 2; L++)
            gA[H][L] = A + (size_t)(Mbase + H * 128 + L * 64 + srow) * K + sl * 8;
#pragma unroll
    for (int L = 0; L < 3; L++)
        gBv[L] = Bw + (size_t)(Nbase + L * 64 + srow) * K + sl * 8;
    const int dOffW = w * 512;                   // wave-uniform LDS dest (u16)

    int offA[4][2], offB[3][2];
    const int xsw = lc & 7;
#pragma unroll
    for (int mi = 0; mi < 4; mi++)
#pragma unroll
        for (int kk = 0; kk < 2; kk++)
            offA[mi][kk] = (wm * 64 + mi * 16 + lc) * 64 + (((kk * 4 + quad) ^ xsw) * 8);
#pragma unroll
    for (int nj = 0; nj < 3; nj++)
#pragma unroll
        for (int kk = 0; kk < 2; kk++)
            offB[nj][kk] = (wn * 48 + nj * 16 + lc) * 64 + (((kk * 4 + quad) ^ xsw) * 8);

    floatx4 acc[2][4][3] = {};                   // [AH][mi][nj]

    STGALL(0, 0);
    WAITZ;
    FENCE; __builtin_amdgcn_s_barrier(); FENCE;

    const int NT = K >> 6;                       // 64 for K=4096
    for (int t = 0; t < NT - 2; t += 2) {
        PH1(0, STGALL(1, t + 1), WAITZ);
        PH1(1, STGALL(0, t + 2), WAITZ);
    }
    PH1(0, STGALL(1, NT - 1), WAITZ);
    PH1(1, NOSTG, NOW);

    // epilogue C write (C/D layout: col = lane&15, row = quad*4 + r)
#pragma unroll
    for (int AH = 0; AH < 2; AH++)
#pragma unroll
        for (int mi = 0; mi < 4; mi++) {
            const int row0 = Mbase + AH * 128 + wm * 64 + mi * 16 + quad * 4;
#pragma unroll
            for (int nj = 0; nj < 3; nj++) {
                const int col = Nbase + wn * 48 + nj * 16 + lc;
#pragma unroll
                for (int r = 0; r < 4; r++)
                    Cv[(size_t)(row0 + r) * N + col] = f2b(acc[AH][mi][nj][r]);
            }
        }
}
#undef HBA
#undef HBB
#undef STGA
#undef STGB
#undef STGALL
#undef PH1

// ---------------- GEMM2: C[M,N](f32) = A[M,K] * B[N,K]^T, 128x256 tile ----------------
// Full-machine grid (16x16=256 blocks). 8 waves, per-wave 64x64. R9/R10 single-phase.
// R16 XCD swizzle KEPT (neutral-to-positive per R17 decomposition).
#define HA2(BUF, H) (lds + (BUF) * 24576 + (H) * 4096)
#define HBB2(BUF)   (lds + (BUF) * 24576 + 8192)
#define STGA2(BUF, H, KT) gload_lds16(gA2[H] + (size_t)(KT) * 64, HA2(BUF, H) + dOffW)
#define STGB2(BUF, KT) do { \
    _Pragma("unroll") \
    for (int _L = 0; _L < 4; _L++) \
        gload_lds16(gB2[_L] + (size_t)(KT) * 64, HBB2(BUF) + _L * 4096 + dOffW); \
} while (0)
#define STGALL2(BUF, KT) do { STGA2(BUF, 0, KT); STGA2(BUF, 1, KT); STGB2(BUF, KT); } while (0)
#define PH2(CBUF, STAGES, ENDW) do { \
    const u16* _pa0 = HA2(CBUF, 0); \
    const u16* _pa1 = HA2(CBUF, 1); \
    const u16* _pb  = HBB2(CBUF); \
    short8x af0[2][2], af1[2][2], bf2[4][2]; \
    _Pragma("unroll") \
    for (int _mi = 0; _mi < 2; _mi++) { \
        af0[_mi][0] = *(const short8x*)(_pa0 + offA2[_mi][0]); \
        af0[_mi][1] = *(const short8x*)(_pa0 + offA2[_mi][1]); } \
    _Pragma("unroll") \
    for (int _nj = 0; _nj < 4; _nj++) { \
        bf2[_nj][0] = *(const short8x*)(_pb + offB2[_nj][0]); \
        bf2[_nj][1] = *(const short8x*)(_pb + offB2[_nj][1]); } \
    STAGES; \
    __builtin_amdgcn_sched_barrier(0); \
    _Pragma("unroll") \
    for (int _mi = 0; _mi < 2; _mi++) { \
        af1[_mi][0] = *(const short8x*)(_pa1 + offA2[_mi][0]); \
        af1[_mi][1] = *(const short8x*)(_pa1 + offA2[_mi][1]); } \
    __builtin_amdgcn_s_setprio(1); \
    _Pragma("unroll") \
    for (int _kk = 0; _kk < 2; _kk++) \
        _Pragma("unroll") \
        for (int _mi = 0; _mi < 2; _mi++) \
            _Pragma("unroll") \
            for (int _nj = 0; _nj < 4; _nj++) \
                acc2[0][_mi][_nj] = __builtin_amdgcn_mfma_f32_16x16x32_bf16( \
                    af0[_mi][_kk], bf2[_nj][_kk], acc2[0][_mi][_nj], 0, 0, 0); \
    _Pragma("unroll") \
    for (int _kk = 0; _kk < 2; _kk++) \
        _Pragma("unroll") \
        for (int _mi = 0; _mi < 2; _mi++) \
            _Pragma("unroll") \
            for (int _nj = 0; _nj < 4; _nj++) \
                acc2[1][_mi][_nj] = __builtin_amdgcn_mfma_f32_16x16x32_bf16( \
                    af1[_mi][_kk], bf2[_nj][_kk], acc2[1][_mi][_nj], 0, 0, 0); \
    __builtin_amdgcn_s_setprio(0); \
    ENDW; \
    FENCE; __builtin_amdgcn_s_barrier(); FENCE; \
} while (0)

__global__ __launch_bounds__(512, 1) void gemmko_kernel(
    const u16* __restrict__ A, const u16* __restrict__ Bw,
    float* __restrict__ C, int N, int K) {
    extern __shared__ __align__(16) u16 lds[];   // 96 KiB dynamic
    const int tid = threadIdx.x;
    const int lane = tid & 63, w = tid >> 6;
    const int quad = lane >> 4, lc = lane & 15;
    const int wm = (w >> 2) & 1, wn = w & 3;     // 2M x 4N wave grid
    const int n = blockIdx.x + (blockIdx.y << 4);         // linear dispatch id
    const int by = ((n & 7) << 1) + ((n >> 3) & 1);       // XCD swizzle
    const int bx = n >> 4;
    const int Mbase = by * 128, Nbase = bx * 256;

    const int r8 = lane >> 3;
    const int sl = (lane & 7) ^ r8;              // pre-swizzled 16B slot
    const int srow = w * 8 + r8;                 // 0..63 within a 64-row unit
    const u16* gA2[2];
    const u16* gB2[4];
#pragma unroll
    for (int H = 0; H < 2; H++)
        gA2[H] = A + (size_t)(Mbase + H * 64 + srow) * K + sl * 8;
#pragma unroll
    for (int L = 0; L < 4; L++)
        gB2[L] = Bw + (size_t)(Nbase + L * 64 + srow) * K + sl * 8;
    const int dOffW = w * 512;                   // wave-uniform LDS dest (u16)

    int offA2[2][2], offB2[4][2];
    const int xsw = lc & 7;
#pragma unroll
    for (int mi = 0; mi < 2; mi++)
#pragma unroll
        for (int kk = 0; kk < 2; kk++)
            offA2[mi][kk] = (wm * 32 + mi * 16 + lc) * 64 + (((kk * 4 + quad) ^ xsw) * 8);
#pragma unroll
    for (int nj = 0; nj < 4; nj++)
#pragma unroll
        for (int kk = 0; kk < 2; kk++)
            offB2[nj][kk] = (wn * 64 + nj * 16 + lc) * 64 + (((kk * 4 + quad) ^ xsw) * 8);

    floatx4 acc2[2][2][4] = {};                  // [AH][mi][nj]

    STGALL2(0, 0);
    WAITZ;
    FENCE; __builtin_amdgcn_s_barrier(); FENCE;

    const int NT = K >> 6;                       // 64
    for (int t = 0; t < NT - 2; t += 2) {
        PH2(0, STGALL2(1, t + 1), WAITZ);
        PH2(1, STGALL2(0, t + 2), WAITZ);
    }
    PH2(0, STGALL2(1, NT - 1), WAITZ);
    PH2(1, NOSTG, NOW);

    // epilogue (f32 out)
#pragma unroll
    for (int AH = 0; AH < 2; AH++)
#pragma unroll
        for (int mi = 0; mi < 2; mi++) {
            const int row0 = Mbase + AH * 64 + wm * 32 + mi * 16 + quad * 4;
#pragma unroll
            for (int nj = 0; nj < 4; nj++) {
                const int col = Nbase + wn * 64 + nj * 16 + lc;
#pragma unroll
                for (int r = 0; r < 4; r++)
                    C[(size_t)(row0 + r) * N + col] = acc2[AH][mi][nj][r];
            }
        }
}
#undef HA2
#undef HBB2
#undef STGA2
#undef STGB2
#undef STGALL2
#undef PH2
#undef WAITZ
#undef NOSTG
#undef NOW
#undef FENCE

// ---------------- cache prefix copy (no-op when start_pos==0) ----------------
__global__ void cache_prefix_kernel(const float* __restrict__ ck, const float* __restrict__ cv,
                                    const int* __restrict__ sp,
                                    u16* __restrict__ kh, u16* __restrict__ vt8) {
    int spos = sp[0];
    long total = (long)2 * spos * NKVH * HD;
    for (long i = (long)blockIdx.x * blockDim.x + threadIdx.x; i < total; i += (long)gridDim.x * blockDim.x) {
        long d = i % HD, rest = i / HD;
        long g = rest % NKVH; rest /= NKVH;
        long s = rest % spos; long b = rest / spos;
        float kv = ck[((b * SMAX + s) * NKVH + g) * HD + d];
        kh[((b * NKVH + g) * SMAX + s) * HD + d] = f2b(kv);
        float vv = cv[((b * SMAX + s) * NKVH + g) * HD + d];
        vt8[(size_t)(b * NKVH + g) * SMAX * HD + (s >> 3) * 1024 + d * 8 + (s & 7)] = f2b(vv);
    }
}

// ---------------- RoPE for Q and K (reads bf16 qkv) ----------------
__global__ void rope_qk_kernel(const u16* __restrict__ qkvb, const int* __restrict__ sp,
                               u16* __restrict__ qh, u16* __restrict__ kh) {
    int spos = sp[0];
    int idx = blockIdx.x * blockDim.x + threadIdx.x;   // tok*2560 + u
    int tok = idx / 2560;
    int u = idx - tok * 2560;
    int b = tok >> 10, t = tok & 1023;
    float pos = (float)(spos + t);
    const u16* src = qkvb + (size_t)tok * QKVN;
    const float kScale = 0.08838834764831845f;  // 1/sqrt(128)
    const float kLog = -0.20762050593045857f;   // -log2(10000)/64
    if (u < 2048) {                 // q: 32 heads x 64 pairs
        int h = u >> 6, i = u & 63;
        float ang = pos * exp2f((float)i * kLog);
        float cs = cosf(ang), sn = sinf(ang);
        float x0 = b2f(src[h * HD + 2 * i]), x1 = b2f(src[h * HD + 2 * i + 1]);
        size_t dst = (((size_t)(b * NQH + h) * T_SEQ) + t) * HD + 2 * i;
        qh[dst]     = f2b((x0 * cs - x1 * sn) * kScale);
        qh[dst + 1] = f2b((x0 * sn + x1 * cs) * kScale);
    } else {                        // k: 8 heads x 64 pairs
        int u2 = u - 2048;
        int g = u2 >> 6, i = u2 & 63;
        float ang = pos * exp2f((float)i * kLog);
        float cs = cosf(ang), sn = sinf(ang);
        float x0 = b2f(src[EMBED + g * HD + 2 * i]), x1 = b2f(src[EMBED + g * HD + 2 * i + 1]);
        size_t dst = (((size_t)(b * NKVH + g) * SMAX) + spos + t) * HD + 2 * i;
        kh[dst]     = f2b(x0 * cs - x1 * sn);
        kh[dst + 1] = f2b(x0 * sn + x1 * cs);
    }
}

// ---------------- V pack: bf16 qkv -> 8-token-interleaved vt8 (LDS transpose) ----------------
__global__ __launch_bounds__(256) void vpack_kernel(const u16* __restrict__ qkvb,
                                                    const int* __restrict__ sp,
                                                    u16* __restrict__ vt8) {
    __shared__ u16 lds[16 * 136];
    int spos = sp[0];
    int tile = blockIdx.x;          // b*512 + g*64 + t16
    int t16 = tile & 63;
    int g = (tile >> 6) & 7;
    int b = tile >> 9;
    int tok0 = t16 * 16;
    int tid = threadIdx.x;
    {
        int srow = tid >> 4, dc8 = (tid & 15) * 8;
        const u16* src = qkvb + (size_t)(b * T_SEQ + tok0 + srow) * QKVN + 5120 + g * HD + dc8;
        *(uint4*)(lds + srow * 136 + dc8) = *(const uint4*)src;
    }
    __syncthreads();
    int d = tid & 127, half = tid >> 7;
    u16* vpg = vt8 + (size_t)(b * NKVH + g) * SMAX * HD;
    int s0 = spos + tok0;
    u16 val[8];
#pragma unroll
    for (int k = 0; k < 8; k++) val[k] = lds[(half * 8 + k) * 136 + d];
    if ((s0 & 7) == 0) {
        union { u16 h[8]; uint4 u; } pk;
#pragma unroll
        for (int k = 0; k < 8; k++) pk.h[k] = val[k];
        *(uint4*)(vpg + (size_t)((s0 >> 3) + half) * 1024 + d * 8) = pk.u;
    } else {
#pragma unroll
        for (int k = 0; k < 8; k++) {
            int s = s0 + half * 8 + k;
            vpg[(size_t)(s >> 3) * 1024 + d * 8 + (s & 7)] = val[k];
        }
    }
}

// ---------------- causal GQA flash attention v4 + XCD swizzle + Wo converter ----------------
// Blocks 0..1023: attn, byte-identical to R17 (XCD swizzle pins each (b,g)'s
// 2MB K/V panels to one XCD's L2 -- the R15 win; launch_bounds (256,2), R14:
// raising it spills). Blocks 1024..1535: Wo f32->bf16 conversion companion
// blocks -- dispatched LAST, they fill CUs as attn's short-tile tail drains,
// overlapping ~15us of BW work with latency-bound attn. Nontemporal accesses
// avoid evicting attn's L2-resident K/V. wob is complete before gemmko (same
// kernel, stream-ordered).
__global__ __launch_bounds__(256, 2) void attn_kernel(
    const u16* __restrict__ qh, const u16* __restrict__ kh,
    const u16* __restrict__ vt8, const int* __restrict__ sp,
    u16* __restrict__ ctx,
    const float* __restrict__ WoF, u16* __restrict__ wob) {
    extern __shared__ __align__(16) char smem[];
    int tid = threadIdx.x;
    int bid = blockIdx.x;
    if (bid >= 1024) {
        // ---- Wo converter: 512 blocks x 256 thr x 32 iters of 16B ----
        const f32x4* src = (const f32x4*)WoF;
        u32x2* dst = (u32x2*)wob;
        for (int i = (bid - 1024) * 256 + tid; i < 4194304; i += 131072) {
            f32x4 f = __builtin_nontemporal_load(src + i);
            union { u16 h[4]; u32x2 v; } o;
            o.h[0] = f2b(f[0]); o.h[1] = f2b(f[1]);
            o.h[2] = f2b(f[2]); o.h[3] = f2b(f[3]);
            __builtin_nontemporal_store(o.v, dst + i);
        }
        return;
    }
    int spos = sp[0];
    int w = tid >> 6, lane = tid & 63;
    int quad = lane >> 4, lc = lane & 15;
    int tile = (bid & 7) * 128 + (bid >> 3);   // XCD-aware swizzle (bijective)
    int j = 63 - (tile & 63);       // longest-first dispatch
    int g = (tile >> 6) & 7;
    int b = tile >> 9;
    int qbase = j * 16;

    const u16* kp = kh + (size_t)(b * NKVH + g) * SMAX * HD;
    const u16* vp = vt8 + (size_t)(b * NKVH + g) * SMAX * HD;

    short8x qf[4][4];
#pragma unroll
    for (int m = 0; m < 4; m++) {
        const u16* qp = qh + ((size_t)(b * NQH + g * 4 + m) * T_SEQ + qbase + lc) * HD + quad * 8;
#pragma unroll
        for (int dc = 0; dc < 4; dc++)
            qf[m][dc] = *(const short8x*)(qp + dc * 32);
    }
    short8x ones;
#pragma unroll
    for (int jj = 0; jj < 8; jj++) ones[jj] = (short)0x3F80;   // bf16 1.0

    floatx4 o[4][8] = {};
    floatx4 lacc[4] = {};
    int rowpos = spos + qbase + quad * 4;      // +r = absolute query position
    int nch = (spos + qbase + 16 + 63) >> 6;   // 64-key chunks
    u16* pw = (u16*)smem + w * 4608;           // this wave's P buffer (4 tiles x 16x72)

    for (int c = w; c < nch; c += 4) {
        int koff = c * 64;
#pragma unroll
        for (int st = 0; st < 4; st++) {
            const u16* kr = kp + (size_t)(koff + st * 16 + lc) * HD + quad * 8;
            floatx4 sc[4] = {};
#pragma unroll
            for (int dc = 0; dc < 4; dc++) {
                short8x kf = *(const short8x*)(kr + dc * 32);
#pragma unroll
                for (int m = 0; m < 4; m++)
                    sc[m] = __builtin_amdgcn_mfma_f32_16x16x32_bf16(qf[m][dc], kf, sc[m], 0, 0, 0);
            }
            int skey = koff + st * 16 + lc;
#pragma unroll
            for (int m = 0; m < 4; m++)
#pragma unroll
                for (int r = 0; r < 4; r++) {
                    float p = (skey <= rowpos + r) ? __expf(sc[m][r]) : 0.0f;
                    pw[m * 1152 + (quad * 4 + r) * 72 + st * 16 + lc] = f2b(p);
                }
        }
        asm volatile("s_waitcnt lgkmcnt(0)" ::: "memory");
#pragma unroll
        for (int hf = 0; hf < 2; hf++) {
            short8x pf[4];
#pragma unroll
            for (int m = 0; m < 4; m++)
                pf[m] = *(const short8x*)(pw + m * 1152 + lc * 72 + hf * 32 + quad * 8);
#pragma unroll
            for (int m = 0; m < 4; m++)
                lacc[m] = __builtin_amdgcn_mfma_f32_16x16x32_bf16(pf[m], ones, lacc[m], 0, 0, 0);
            const u16* vbase = vp + ((size_t)koff << 7) + (size_t)(hf * 4 + quad) * 1024 + lc * 8;
#pragma unroll
            for (int dc8 = 0; dc8 < 8; dc8++) {
                short8x vf = *(const short8x*)(vbase + dc8 * 128);
#pragma unroll
                for (int m = 0; m < 4; m++)
                    o[m][dc8] = __builtin_amdgcn_mfma_f32_16x16x32_bf16(pf[m], vf, o[m][dc8], 0, 0, 0);
            }
        }
    }

    // phased fp32 combine across the 4 waves (obuf aliases pbuf -- safe after barrier)
    float* obuf = (float*)smem;                 // 64 x 132
    float* lbuf = (float*)(smem + 33792);       // 64
    for (int ph = 0; ph < 4; ph++) {
        __syncthreads();
        if (w == ph) {
            if (ph == 0) {
#pragma unroll
                for (int m = 0; m < 4; m++) {
#pragma unroll
                    for (int dc8 = 0; dc8 < 8; dc8++)
#pragma unroll
                        for (int r = 0; r < 4; r++)
                            obuf[(m * 16 + quad * 4 + r) * 132 + dc8 * 16 + lc] = o[m][dc8][r];
#pragma unroll
                    for (int r = 0; r < 4; r++) lbuf[m * 16 + quad * 4 + r] = lacc[m][r];
                }
            } else {
#pragma unroll
                for (int m = 0; m < 4; m++) {
#pragma unroll
                    for (int dc8 = 0; dc8 < 8; dc8++)
#pragma unroll
                        for (int r = 0; r < 4; r++)
                            obuf[(m * 16 + quad * 4 + r) * 132 + dc8 * 16 + lc] += o[m][dc8][r];
#pragma unroll
                    for (int r = 0; r < 4; r++) lbuf[m * 16 + quad * 4 + r] += lacc[m][r];
                }
            }
        }
    }
    __syncthreads();

    // cooperative normalize + store: thread -> (row = tid/4, 32 cols)
    int row = tid >> 2;                 // 0..63: head m = row>>4, token off = row&15
    int m = row >> 4;
    int cb = (tid & 3) * 32;
    float inv = 1.0f / lbuf[row];
    int token = qbase + (row & 15);
    size_t base = ((size_t)(b * T_SEQ + token) * NQH + g * 4 + m) * HD + cb;
#pragma unroll
    for (int v4 = 0; v4 < 4; v4++) {
        union { u16 h[8]; uint4 u; } pk;
#pragma unroll
        for (int jj = 0; jj < 8; jj++)
            pk.h[jj] = f2b(obuf[row * 132 + cb + v4 * 8 + jj] * inv);
        *(uint4*)(ctx + base + v4 * 8) = pk.u;
    }
}

extern "C" void kernel_launch(void* const* d_in, const int* in_sizes, int n_in,
                              void* d_out, int out_size, void* d_ws, size_t ws_size,
                              hipStream_t stream) {
    const float* x  = (const float*)d_in[0];
    const float* Wq = (const float*)d_in[1];
    const float* Wk = (const float*)d_in[2];
    const float* Wv = (const float*)d_in[3];
    const float* Wo = (const float*)d_in[4];
    const float* ck = (const float*)d_in[5];
    const float* cv = (const float*)d_in[6];
    const int*   sp = (const int*)d_in[7];

    char* p = (char*)d_ws;
    u16* xb   = (u16*)p;                                  // x bf16 (dead after GEMM1)
    u16* qh   = xb;                                       //   aliased: q_h after GEMM1
    p += (size_t)TOKENS * EMBED * 2;                      // 16 MB
    u16* wqkv = (u16*)p; p += (size_t)QKVN * EMBED * 2;   // 48 MB
    u16* wob  = (u16*)p; p += (size_t)EMBED * EMBED * 2;  // 32 MB
    u16* qkvb = (u16*)p;                                  // 24 MB bf16 (dead after rope+vpack)
    u16* ctx  = qkvb;                                     //   aliased: ctx (16 MB) after vpack
    p += (size_t)TOKENS * QKVN * 2;
    u16* kh   = (u16*)p; p += (size_t)2 * NKVH * SMAX * HD * 2;  // 8 MB
    u16* vt8  = (u16*)p;                                         // 8 MB

    static int gemm_attr = 0;
    if (!gemm_attr) {
        (void)hipFuncSetAttribute(reinterpret_cast<const void*>(&gemm256_kernel),
                                  hipFuncAttributeMaxDynamicSharedMemorySize, 114688);
        (void)hipFuncSetAttribute(reinterpret_cast<const void*>(&gemmko_kernel),
                                  hipFuncAttributeMaxDynamicSharedMemorySize, 98304);
        (void)hipFuncSetAttribute(reinterpret_cast<const void*>(&attn_kernel),
                                  hipFuncAttributeMaxDynamicSharedMemorySize, 36864);
        gemm_attr = 1;
    }

    convert_all_kernel<<<(CSEG3 + 255) / 256, 256, 0, stream>>>(x, Wq, Wk, Wv, xb, wqkv);
    gemm256_kernel<<<dim3(QKVN / 192, TOKENS / 256), 512, 114688, stream>>>(xb, wqkv, qkvb, QKVN, EMBED);
    cache_prefix_kernel<<<256, 256, 0, stream>>>(ck, cv, sp, kh, vt8);
    rope_qk_kernel<<<TOKENS * 2560 / 256, 256, 0, stream>>>(qkvb, sp, qh, kh);
    vpack_kernel<<<1024, 256, 0, stream>>>(qkvb, sp, vt8);
    attn_kernel<<<1536, 256, 36864, stream>>>(qh, kh, vt8, sp, ctx, Wo, wob);
    gemmko_kernel<<<dim3(EMBED / 256, TOKENS / 128), 512, 98304, stream>>>(ctx, wob, (float*)d_out, EMBED, EMBED);
}

// Round 20
// 281.019 us; speedup vs baseline: 1.0737x; 1.0737x over previous
//
#include <hip/hip_runtime.h>
#include <stdint.h>

typedef unsigned short u16;
typedef __attribute__((ext_vector_type(8))) short short8x;   // 8 x bf16 (4 VGPRs)
typedef __attribute__((ext_vector_type(4))) float floatx4;   // MFMA C/D

#define TOKENS 2048   // B*T
#define EMBED  4096
#define QKVN   6144   // 4096 q + 1024 k + 1024 v
#define T_SEQ  1024
#define SMAX   2048   // cache length (2*KV_SEQ_LEN)
#define NQH    32
#define NKVH   8
#define HD     128

// RNE f32 -> bf16 (finite inputs only)
static __device__ __forceinline__ u16 f2b(float f) {
    union { float f; uint32_t u; } v; v.f = f;
    uint32_t r = v.u + 0x7fffu + ((v.u >> 16) & 1u);
    return (u16)(r >> 16);
}
static __device__ __forceinline__ float b2f(u16 h) {
    union { uint32_t u; float f; } v; v.u = ((uint32_t)h) << 16; return v.f;
}

static __device__ __forceinline__ void gload_lds16(const u16* g, u16* l) {
    __builtin_amdgcn_global_load_lds(
        (const __attribute__((address_space(1))) uint32_t*)g,
        (__attribute__((address_space(3))) uint32_t*)l, 16, 0, 0);
}

// ---------------- fused f32 -> bf16 conversion for all 5 inputs ----------------
// R20: reverted R18's Wo-fusion into attn (regressed 281.7->301.7: the 96MB
// converter stream interfered with attn's latency-bound K/V chain instead of
// overlapping its tail). Full 288MB conversion here, at BW ceiling.
#define CSEG0 2097152              // x        (2048*4096/4)
#define CSEG1 6291456              // +Wq      (4096*4096/4)
#define CSEG2 7340032              // +Wk      (1024*4096/4)
#define CSEG3 8388608              // +Wv      (1024*4096/4)
#define CSEG4 12582912             // +Wo      (4096*4096/4)
__global__ void convert_all_kernel(const float* __restrict__ x,  const float* __restrict__ Wq,
                                   const float* __restrict__ Wk, const float* __restrict__ Wv,
                                   const float* __restrict__ Wo,
                                   u16* __restrict__ xb, u16* __restrict__ wqkv,
                                   u16* __restrict__ wob) {
    int i = blockIdx.x * blockDim.x + threadIdx.x;   // float4 index
    if (i >= CSEG4) return;
    const float4* src; uint2* dst; int off;
    if (i < CSEG0)      { src = (const float4*)x;  dst = (uint2*)xb;   off = i; }
    else if (i < CSEG1) { src = (const float4*)Wq; dst = (uint2*)wqkv; off = i - CSEG0; }
    else if (i < CSEG2) { src = (const float4*)Wk; dst = (uint2*)wqkv + 4194304; off = i - CSEG1; }
    else if (i < CSEG3) { src = (const float4*)Wv; dst = (uint2*)wqkv + 5242880; off = i - CSEG2; }
    else                { src = (const float4*)Wo; dst = (uint2*)wob;  off = i - CSEG3; }
    float4 f = src[off];
    union { u16 h[4]; uint2 v; } o;
    o.h[0] = f2b(f.x); o.h[1] = f2b(f.y); o.h[2] = f2b(f.z); o.h[3] = f2b(f.w);
    dst[off] = o.v;
}

#define FENCE asm volatile("" ::: "memory")
#define WAITZ asm volatile("s_waitcnt vmcnt(0)" ::: "memory")
#define NOSTG ((void)0)
#define NOW   ((void)0)

// ---------------- GEMM1: C[M,N] = A[M,K] * B[N,K]^T, 256x192 tile ----------------
// R10 schedule (107 us, MfmaUtil 42%). Full-machine grid (32x8). 8 waves (2M x 4N),
// per-wave 128x48, BK=64, ONE phase/K-tile: af0+bf blocking reads, stage(t+1),
// sched_barrier, af1 reads overlapped under first MFMA cluster, vmcnt(0)+barrier.
// Default dispatch (R16 swizzle hurt here: B-sharing moved cross-XCD, FETCH 2.2x).
#define HBA(BUF, H) (lds + (BUF) * 28672 + (H) * 8192)
#define HBB(BUF)    (lds + (BUF) * 28672 + 16384)
#define STGA(BUF, H, KT) do { \
    gload_lds16(gA[H][0] + (size_t)(KT) * 64, HBA(BUF, H) + dOffW); \
    gload_lds16(gA[H][1] + (size_t)(KT) * 64, HBA(BUF, H) + 4096 + dOffW); \
} while (0)
#define STGB(BUF, KT) do { \
    _Pragma("unroll") \
    for (int _L = 0; _L < 3; _L++) \
        gload_lds16(gBv[_L] + (size_t)(KT) * 64, HBB(BUF) + _L * 4096 + dOffW); \
} while (0)
#define STGALL(BUF, KT) do { STGA(BUF, 0, KT); STGA(BUF, 1, KT); STGB(BUF, KT); } while (0)
#define PH1(CBUF, STAGES, ENDW) do { \
    const u16* _pa0 = HBA(CBUF, 0); \
    const u16* _pa1 = HBA(CBUF, 1); \
    const u16* _pb  = HBB(CBUF); \
    short8x af0[4][2], af1[4][2], bf[3][2]; \
    _Pragma("unroll") \
    for (int _mi = 0; _mi < 4; _mi++) { \
        af0[_mi][0] = *(const short8x*)(_pa0 + offA[_mi][0]); \
        af0[_mi][1] = *(const short8x*)(_pa0 + offA[_mi][1]); } \
    _Pragma("unroll") \
    for (int _nj = 0; _nj < 3; _nj++) { \
        bf[_nj][0] = *(const short8x*)(_pb + offB[_nj][0]); \
        bf[_nj][1] = *(const short8x*)(_pb + offB[_nj][1]); } \
    STAGES; \
    __builtin_amdgcn_sched_barrier(0); \
    _Pragma("unroll") \
    for (int _mi = 0; _mi < 4; _mi++) { \
        af1[_mi][0] = *(const short8x*)(_pa1 + offA[_mi][0]); \
        af1[_mi][1] = *(const short8x*)(_pa1 + offA[_mi][1]); } \
    __builtin_amdgcn_s_setprio(1); \
    _Pragma("unroll") \
    for (int _kk = 0; _kk < 2; _kk++) \
        _Pragma("unroll") \
        for (int _mi = 0; _mi < 4; _mi++) \
            _Pragma("unroll") \
            for (int _nj = 0; _nj < 3; _nj++) \
                acc[0][_mi][_nj] = __builtin_amdgcn_mfma_f32_16x16x32_bf16( \
                    af0[_mi][_kk], bf[_nj][_kk], acc[0][_mi][_nj], 0, 0, 0); \
    _Pragma("unroll") \
    for (int _kk = 0; _kk < 2; _kk++) \
        _Pragma("unroll") \
        for (int _mi = 0; _mi < 4; _mi++) \
            _Pragma("unroll") \
            for (int _nj = 0; _nj < 3; _nj++) \
                acc[1][_mi][_nj] = __builtin_amdgcn_mfma_f32_16x16x32_bf16( \
                    af1[_mi][_kk], bf[_nj][_kk], acc[1][_mi][_nj], 0, 0, 0); \
    __builtin_amdgcn_s_setprio(0); \
    ENDW; \
    FENCE; __builtin_amdgcn_s_barrier(); FENCE; \
} while (0)

__global__ __launch_bounds__(512, 1) void gemm256_kernel(
    const u16* __restrict__ A, const u16* __restrict__ Bw,
    u16* __restrict__ Cv, int N, int K) {
    extern __shared__ __align__(16) u16 lds[];   // 112 KiB dynamic
    const int tid = threadIdx.x;
    const int lane = tid & 63, w = tid >> 6;
    const int quad = lane >> 4, lc = lane & 15;
    const int wm = w >> 2, wn = w & 3;           // 2M x 4N wave grid
    const int Mbase = blockIdx.y * 256, Nbase = blockIdx.x * 192;

    const int r8 = lane >> 3;                    // row within 8-row wave stripe
    const int sl = (lane & 7) ^ r8;              // pre-swizzled 16B slot in row
    const int srow = w * 8 + r8;                 // 0..63 within a 64-row load unit
    const u16* gA[2][2];                         // [half][unit]
    const u16* gBv[3];
#pragma unroll
    for (int H = 0; H < 2; H++)
#pragma unroll
        for (int L = 0; L < 2; L++)
            gA[H][L] = A + (size_t)(Mbase + H * 128 + L * 64 + srow) * K + sl * 8;
#pragma unroll
    for (int L = 0; L < 3; L++)
        gBv[L] = Bw + (size_t)(Nbase + L * 64 + srow) * K + sl * 8;
    const int dOffW = w * 512;                   // wave-uniform LDS dest (u16)

    int offA[4][2], offB[3][2];
    const int xsw = lc & 7;
#pragma unroll
    for (int mi = 0; mi < 4; mi++)
#pragma unroll
        for (int kk = 0; kk < 2; kk++)
            offA[mi][kk] = (wm * 64 + mi * 16 + lc) * 64 + (((kk * 4 + quad) ^ xsw) * 8);
#pragma unroll
    for (int nj = 0; nj < 3; nj++)
#pragma unroll
        for (int kk = 0; kk < 2; kk++)
            offB[nj][kk] = (wn * 48 + nj * 16 + lc) * 64 + (((kk * 4 + quad) ^ xsw) * 8);

    floatx4 acc[2][4][3] = {};                   // [AH][mi][nj]

    STGALL(0, 0);
    WAITZ;
    FENCE; __builtin_amdgcn_s_barrier(); FENCE;

    const int NT = K >> 6;                       // 64 for K=4096
    for (int t = 0; t < NT - 2; t += 2) {
        PH1(0, STGALL(1, t + 1), WAITZ);
        PH1(1, STGALL(0, t + 2), WAITZ);
    }
    PH1(0, STGALL(1, NT - 1), WAITZ);
    PH1(1, NOSTG, NOW);

    // epilogue C write (C/D layout: col = lane&15, row = quad*4 + r)
#pragma unroll
    for (int AH = 0; AH < 2; AH++)
#pragma unroll
        for (int mi = 0; mi < 4; mi++) {
            const int row0 = Mbase + AH * 128 + wm * 64 + mi * 16 + quad * 4;
#pragma unroll
            for (int nj = 0; nj < 3; nj++) {
                const int col = Nbase + wn * 48 + nj * 16 + lc;
#pragma unroll
                for (int r = 0; r < 4; r++)
                    Cv[(size_t)(row0 + r) * N + col] = f2b(acc[AH][mi][nj][r]);
            }
        }
}
#undef HBA
#undef HBB
#undef STGA
#undef STGB
#undef STGALL
#undef PH1

// ---------------- GEMM2: C[M,N](f32) = A[M,K] * B[N,K]^T, 128x256 tile ----------------
// Full-machine grid (16x16=256 blocks). 8 waves, per-wave 64x64. R9/R10 single-phase.
// R16 XCD swizzle KEPT (neutral-to-positive per R17 decomposition).
#define HA2(BUF, H) (lds + (BUF) * 24576 + (H) * 4096)
#define HBB2(BUF)   (lds + (BUF) * 24576 + 8192)
#define STGA2(BUF, H, KT) gload_lds16(gA2[H] + (size_t)(KT) * 64, HA2(BUF, H) + dOffW)
#define STGB2(BUF, KT) do { \
    _Pragma("unroll") \
    for (int _L = 0; _L < 4; _L++) \
        gload_lds16(gB2[_L] + (size_t)(KT) * 64, HBB2(BUF) + _L * 4096 + dOffW); \
} while (0)
#define STGALL2(BUF, KT) do { STGA2(BUF, 0, KT); STGA2(BUF, 1, KT); STGB2(BUF, KT); } while (0)
#define PH2(CBUF, STAGES, ENDW) do { \
    const u16* _pa0 = HA2(CBUF, 0); \
    const u16* _pa1 = HA2(CBUF, 1); \
    const u16* _pb  = HBB2(CBUF); \
    short8x af0[2][2], af1[2][2], bf2[4][2]; \
    _Pragma("unroll") \
    for (int _mi = 0; _mi < 2; _mi++) { \
        af0[_mi][0] = *(const short8x*)(_pa0 + offA2[_mi][0]); \
        af0[_mi][1] = *(const short8x*)(_pa0 + offA2[_mi][1]); } \
    _Pragma("unroll") \
    for (int _nj = 0; _nj < 4; _nj++) { \
        bf2[_nj][0] = *(const short8x*)(_pb + offB2[_nj][0]); \
        bf2[_nj][1] = *(const short8x*)(_pb + offB2[_nj][1]); } \
    STAGES; \
    __builtin_amdgcn_sched_barrier(0); \
    _Pragma("unroll") \
    for (int _mi = 0; _mi < 2; _mi++) { \
        af1[_mi][0] = *(const short8x*)(_pa1 + offA2[_mi][0]); \
        af1[_mi][1] = *(const short8x*)(_pa1 + offA2[_mi][1]); } \
    __builtin_amdgcn_s_setprio(1); \
    _Pragma("unroll") \
    for (int _kk = 0; _kk < 2; _kk++) \
        _Pragma("unroll") \
        for (int _mi = 0; _mi < 2; _mi++) \
            _Pragma("unroll") \
            for (int _nj = 0; _nj < 4; _nj++) \
                acc2[0][_mi][_nj] = __builtin_amdgcn_mfma_f32_16x16x32_bf16( \
                    af0[_mi][_kk], bf2[_nj][_kk], acc2[0][_mi][_nj], 0, 0, 0); \
    _Pragma("unroll") \
    for (int _kk = 0; _kk < 2; _kk++) \
        _Pragma("unroll") \
        for (int _mi = 0; _mi < 2; _mi++) \
            _Pragma("unroll") \
            for (int _nj = 0; _nj < 4; _nj++) \
                acc2[1][_mi][_nj] = __builtin_amdgcn_mfma_f32_16x16x32_bf16( \
                    af1[_mi][_kk], bf2[_nj][_kk], acc2[1][_mi][_nj], 0, 0, 0); \
    __builtin_amdgcn_s_setprio(0); \
    ENDW; \
    FENCE; __builtin_amdgcn_s_barrier(); FENCE; \
} while (0)

__global__ __launch_bounds__(512, 1) void gemmko_kernel(
    const u16* __restrict__ A, const u16* __restrict__ Bw,
    float* __restrict__ C, int N, int K) {
    extern __shared__ __align__(16) u16 lds[];   // 96 KiB dynamic
    const int tid = threadIdx.x;
    const int lane = tid & 63, w = tid >> 6;
    const int quad = lane >> 4, lc = lane & 15;
    const int wm = (w >> 2) & 1, wn = w & 3;     // 2M x 4N wave grid
    const int n = blockIdx.x + (blockIdx.y << 4);         // linear dispatch id
    const int by = ((n & 7) << 1) + ((n >> 3) & 1);       // XCD swizzle
    const int bx = n >> 4;
    const int Mbase = by * 128, Nbase = bx * 256;

    const int r8 = lane >> 3;
    const int sl = (lane & 7) ^ r8;              // pre-swizzled 16B slot
    const int srow = w * 8 + r8;                 // 0..63 within a 64-row unit
    const u16* gA2[2];
    const u16* gB2[4];
#pragma unroll
    for (int H = 0; H < 2; H++)
        gA2[H] = A + (size_t)(Mbase + H * 64 + srow) * K + sl * 8;
#pragma unroll
    for (int L = 0; L < 4; L++)
        gB2[L] = Bw + (size_t)(Nbase + L * 64 + srow) * K + sl * 8;
    const int dOffW = w * 512;                   // wave-uniform LDS dest (u16)

    int offA2[2][2], offB2[4][2];
    const int xsw = lc & 7;
#pragma unroll
    for (int mi = 0; mi < 2; mi++)
#pragma unroll
        for (int kk = 0; kk < 2; kk++)
            offA2[mi][kk] = (wm * 32 + mi * 16 + lc) * 64 + (((kk * 4 + quad) ^ xsw) * 8);
#pragma unroll
    for (int nj = 0; nj < 4; nj++)
#pragma unroll
        for (int kk = 0; kk < 2; kk++)
            offB2[nj][kk] = (wn * 64 + nj * 16 + lc) * 64 + (((kk * 4 + quad) ^ xsw) * 8);

    floatx4 acc2[2][2][4] = {};                  // [AH][mi][nj]

    STGALL2(0, 0);
    WAITZ;
    FENCE; __builtin_amdgcn_s_barrier(); FENCE;

    const int NT = K >> 6;                       // 64
    for (int t = 0; t < NT - 2; t += 2) {
        PH2(0, STGALL2(1, t + 1), WAITZ);
        PH2(1, STGALL2(0, t + 2), WAITZ);
    }
    PH2(0, STGALL2(1, NT - 1), WAITZ);
    PH2(1, NOSTG, NOW);

    // epilogue (f32 out)
#pragma unroll
    for (int AH = 0; AH < 2; AH++)
#pragma unroll
        for (int mi = 0; mi < 2; mi++) {
            const int row0 = Mbase + AH * 64 + wm * 32 + mi * 16 + quad * 4;
#pragma unroll
            for (int nj = 0; nj < 4; nj++) {
                const int col = Nbase + wn * 64 + nj * 16 + lc;
#pragma unroll
                for (int r = 0; r < 4; r++)
                    C[(size_t)(row0 + r) * N + col] = acc2[AH][mi][nj][r];
            }
        }
}
#undef HA2
#undef HBB2
#undef STGA2
#undef STGB2
#undef STGALL2
#undef PH2
#undef WAITZ
#undef NOSTG
#undef NOW
#undef FENCE

// ---------------- cache prefix copy (no-op when start_pos==0) ----------------
__global__ void cache_prefix_kernel(const float* __restrict__ ck, const float* __restrict__ cv,
                                    const int* __restrict__ sp,
                                    u16* __restrict__ kh, u16* __restrict__ vt8) {
    int spos = sp[0];
    long total = (long)2 * spos * NKVH * HD;
    for (long i = (long)blockIdx.x * blockDim.x + threadIdx.x; i < total; i += (long)gridDim.x * blockDim.x) {
        long d = i % HD, rest = i / HD;
        long g = rest % NKVH; rest /= NKVH;
        long s = rest % spos; long b = rest / spos;
        float kv = ck[((b * SMAX + s) * NKVH + g) * HD + d];
        kh[((b * NKVH + g) * SMAX + s) * HD + d] = f2b(kv);
        float vv = cv[((b * SMAX + s) * NKVH + g) * HD + d];
        vt8[(size_t)(b * NKVH + g) * SMAX * HD + (s >> 3) * 1024 + d * 8 + (s & 7)] = f2b(vv);
    }
}

// ---------------- RoPE for Q and K (reads bf16 qkv) ----------------
__global__ void rope_qk_kernel(const u16* __restrict__ qkvb, const int* __restrict__ sp,
                               u16* __restrict__ qh, u16* __restrict__ kh) {
    int spos = sp[0];
    int idx = blockIdx.x * blockDim.x + threadIdx.x;   // tok*2560 + u
    int tok = idx / 2560;
    int u = idx - tok * 2560;
    int b = tok >> 10, t = tok & 1023;
    float pos = (float)(spos + t);
    const u16* src = qkvb + (size_t)tok * QKVN;
    const float kScale = 0.08838834764831845f;  // 1/sqrt(128)
    const float kLog = -0.20762050593045857f;   // -log2(10000)/64
    if (u < 2048) {                 // q: 32 heads x 64 pairs
        int h = u >> 6, i = u & 63;
        float ang = pos * exp2f((float)i * kLog);
        float cs = cosf(ang), sn = sinf(ang);
        float x0 = b2f(src[h * HD + 2 * i]), x1 = b2f(src[h * HD + 2 * i + 1]);
        size_t dst = (((size_t)(b * NQH + h) * T_SEQ) + t) * HD + 2 * i;
        qh[dst]     = f2b((x0 * cs - x1 * sn) * kScale);
        qh[dst + 1] = f2b((x0 * sn + x1 * cs) * kScale);
    } else {                        // k: 8 heads x 64 pairs
        int u2 = u - 2048;
        int g = u2 >> 6, i = u2 & 63;
        float ang = pos * exp2f((float)i * kLog);
        float cs = cosf(ang), sn = sinf(ang);
        float x0 = b2f(src[EMBED + g * HD + 2 * i]), x1 = b2f(src[EMBED + g * HD + 2 * i + 1]);
        size_t dst = (((size_t)(b * NKVH + g) * SMAX) + spos + t) * HD + 2 * i;
        kh[dst]     = f2b(x0 * cs - x1 * sn);
        kh[dst + 1] = f2b(x0 * sn + x1 * cs);
    }
}

// ---------------- V pack: bf16 qkv -> 8-token-interleaved vt8 (LDS transpose) ----------------
__global__ __launch_bounds__(256) void vpack_kernel(const u16* __restrict__ qkvb,
                                                    const int* __restrict__ sp,
                                                    u16* __restrict__ vt8) {
    __shared__ u16 lds[16 * 136];
    int spos = sp[0];
    int tile = blockIdx.x;          // b*512 + g*64 + t16
    int t16 = tile & 63;
    int g = (tile >> 6) & 7;
    int b = tile >> 9;
    int tok0 = t16 * 16;
    int tid = threadIdx.x;
    {
        int srow = tid >> 4, dc8 = (tid & 15) * 8;
        const u16* src = qkvb + (size_t)(b * T_SEQ + tok0 + srow) * QKVN + 5120 + g * HD + dc8;
        *(uint4*)(lds + srow * 136 + dc8) = *(const uint4*)src;
    }
    __syncthreads();
    int d = tid & 127, half = tid >> 7;
    u16* vpg = vt8 + (size_t)(b * NKVH + g) * SMAX * HD;
    int s0 = spos + tok0;
    u16 val[8];
#pragma unroll
    for (int k = 0; k < 8; k++) val[k] = lds[(half * 8 + k) * 136 + d];
    if ((s0 & 7) == 0) {
        union { u16 h[8]; uint4 u; } pk;
#pragma unroll
        for (int k = 0; k < 8; k++) pk.h[k] = val[k];
        *(uint4*)(vpg + (size_t)((s0 >> 3) + half) * 1024 + d * 8) = pk.u;
    } else {
#pragma unroll
        for (int k = 0; k < 8; k++) {
            int s = s0 + half * 8 + k;
            vpg[(size_t)(s >> 3) * 1024 + d * 8 + (s & 7)] = val[k];
        }
    }
}

// ---------------- causal GQA flash attention v4 + XCD swizzle ----------------
// Wave M=64 rows = 4 Q-heads (one KV group) x 16 tokens. Block = 4 waves on one
// (b,g,16-token tile), 4-way round-robin key split, fp32 LDS combine. Fixed
// softmax max (m=0); row-sum via ones-B MFMA. V in 8-token-interleaved layout.
// R15 win: XCD swizzle pins each (b,g)'s 2MB K/V panels to one XCD's L2 ->
// latency chain L2-class. launch_bounds (256,2): raising it caps regs at 64
// and spills catastrophically (R14). Wo-fusion reverted (R19: -20us).
__global__ __launch_bounds__(256, 2) void attn_kernel(
    const u16* __restrict__ qh, const u16* __restrict__ kh,
    const u16* __restrict__ vt8, const int* __restrict__ sp,
    u16* __restrict__ ctx) {
    extern __shared__ __align__(16) char smem[];
    int spos = sp[0];
    int tid = threadIdx.x, w = tid >> 6, lane = tid & 63;
    int quad = lane >> 4, lc = lane & 15;
    int bid = blockIdx.x;
    int tile = (bid & 7) * 128 + (bid >> 3);   // XCD-aware swizzle (bijective)
    int j = 63 - (tile & 63);       // longest-first dispatch
    int g = (tile >> 6) & 7;
    int b = tile >> 9;
    int qbase = j * 16;

    const u16* kp = kh + (size_t)(b * NKVH + g) * SMAX * HD;
    const u16* vp = vt8 + (size_t)(b * NKVH + g) * SMAX * HD;

    short8x qf[4][4];
#pragma unroll
    for (int m = 0; m < 4; m++) {
        const u16* qp = qh + ((size_t)(b * NQH + g * 4 + m) * T_SEQ + qbase + lc) * HD + quad * 8;
#pragma unroll
        for (int dc = 0; dc < 4; dc++)
            qf[m][dc] = *(const short8x*)(qp + dc * 32);
    }
    short8x ones;
#pragma unroll
    for (int jj = 0; jj < 8; jj++) ones[jj] = (short)0x3F80;   // bf16 1.0

    floatx4 o[4][8] = {};
    floatx4 lacc[4] = {};
    int rowpos = spos + qbase + quad * 4;      // +r = absolute query position
    int nch = (spos + qbase + 16 + 63) >> 6;   // 64-key chunks
    u16* pw = (u16*)smem + w * 4608;           // this wave's P buffer (4 tiles x 16x72)

    for (int c = w; c < nch; c += 4) {
        int koff = c * 64;
#pragma unroll
        for (int st = 0; st < 4; st++) {
            const u16* kr = kp + (size_t)(koff + st * 16 + lc) * HD + quad * 8;
            floatx4 sc[4] = {};
#pragma unroll
            for (int dc = 0; dc < 4; dc++) {
                short8x kf = *(const short8x*)(kr + dc * 32);
#pragma unroll
                for (int m = 0; m < 4; m++)
                    sc[m] = __builtin_amdgcn_mfma_f32_16x16x32_bf16(qf[m][dc], kf, sc[m], 0, 0, 0);
            }
            int skey = koff + st * 16 + lc;
#pragma unroll
            for (int m = 0; m < 4; m++)
#pragma unroll
                for (int r = 0; r < 4; r++) {
                    float p = (skey <= rowpos + r) ? __expf(sc[m][r]) : 0.0f;
                    pw[m * 1152 + (quad * 4 + r) * 72 + st * 16 + lc] = f2b(p);
                }
        }
        asm volatile("s_waitcnt lgkmcnt(0)" ::: "memory");
#pragma unroll
        for (int hf = 0; hf < 2; hf++) {
            short8x pf[4];
#pragma unroll
            for (int m = 0; m < 4; m++)
                pf[m] = *(const short8x*)(pw + m * 1152 + lc * 72 + hf * 32 + quad * 8);
#pragma unroll
            for (int m = 0; m < 4; m++)
                lacc[m] = __builtin_amdgcn_mfma_f32_16x16x32_bf16(pf[m], ones, lacc[m], 0, 0, 0);
            const u16* vbase = vp + ((size_t)koff << 7) + (size_t)(hf * 4 + quad) * 1024 + lc * 8;
#pragma unroll
            for (int dc8 = 0; dc8 < 8; dc8++) {
                short8x vf = *(const short8x*)(vbase + dc8 * 128);
#pragma unroll
                for (int m = 0; m < 4; m++)
                    o[m][dc8] = __builtin_amdgcn_mfma_f32_16x16x32_bf16(pf[m], vf, o[m][dc8], 0, 0, 0);
            }
        }
    }

    // phased fp32 combine across the 4 waves (obuf aliases pbuf -- safe after barrier)
    float* obuf = (float*)smem;                 // 64 x 132
    float* lbuf = (float*)(smem + 33792);       // 64
    for (int ph = 0; ph < 4; ph++) {
        __syncthreads();
        if (w == ph) {
            if (ph == 0) {
#pragma unroll
                for (int m = 0; m < 4; m++) {
#pragma unroll
                    for (int dc8 = 0; dc8 < 8; dc8++)
#pragma unroll
                        for (int r = 0; r < 4; r++)
                            obuf[(m * 16 + quad * 4 + r) * 132 + dc8 * 16 + lc] = o[m][dc8][r];
#pragma unroll
                    for (int r = 0; r < 4; r++) lbuf[m * 16 + quad * 4 + r] = lacc[m][r];
                }
            } else {
#pragma unroll
                for (int m = 0; m < 4; m++) {
#pragma unroll
                    for (int dc8 = 0; dc8 < 8; dc8++)
#pragma unroll
                        for (int r = 0; r < 4; r++)
                            obuf[(m * 16 + quad * 4 + r) * 132 + dc8 * 16 + lc] += o[m][dc8][r];
#pragma unroll
                    for (int r = 0; r < 4; r++) lbuf[m * 16 + quad * 4 + r] += lacc[m][r];
                }
            }
        }
    }
    __syncthreads();

    // cooperative normalize + store: thread -> (row = tid/4, 32 cols)
    int row = tid >> 2;                 // 0..63: head m = row>>4, token off = row&15
    int m = row >> 4;
    int cb = (tid & 3) * 32;
    float inv = 1.0f / lbuf[row];
    int token = qbase + (row & 15);
    size_t base = ((size_t)(b * T_SEQ + token) * NQH + g * 4 + m) * HD + cb;
#pragma unroll
    for (int v4 = 0; v4 < 4; v4++) {
        union { u16 h[8]; uint4 u; } pk;
#pragma unroll
        for (int jj = 0; jj < 8; jj++)
            pk.h[jj] = f2b(obuf[row * 132 + cb + v4 * 8 + jj] * inv);
        *(uint4*)(ctx + base + v4 * 8) = pk.u;
    }
}

extern "C" void kernel_launch(void* const* d_in, const int* in_sizes, int n_in,
                              void* d_out, int out_size, void* d_ws, size_t ws_size,
                              hipStream_t stream) {
    const float* x  = (const float*)d_in[0];
    const float* Wq = (const float*)d_in[1];
    const float* Wk = (const float*)d_in[2];
    const float* Wv = (const float*)d_in[3];
    const float* Wo = (const float*)d_in[4];
    const float* ck = (const float*)d_in[5];
    const float* cv = (const float*)d_in[6];
    const int*   sp = (const int*)d_in[7];

    char* p = (char*)d_ws;
    u16* xb   = (u16*)p;                                  // x bf16 (dead after GEMM1)
    u16* qh   = xb;                                       //   aliased: q_h after GEMM1
    p += (size_t)TOKENS * EMBED * 2;                      // 16 MB
    u16* wqkv = (u16*)p; p += (size_t)QKVN * EMBED * 2;   // 48 MB
    u16* wob  = (u16*)p; p += (size_t)EMBED * EMBED * 2;  // 32 MB
    u16* qkvb = (u16*)p;                                  // 24 MB bf16 (dead after rope+vpack)
    u16* ctx  = qkvb;                                     //   aliased: ctx (16 MB) after vpack
    p += (size_t)TOKENS * QKVN * 2;
    u16* kh   = (u16*)p; p += (size_t)2 * NKVH * SMAX * HD * 2;  // 8 MB
    u16* vt8  = (u16*)p;                                         // 8 MB

    static int gemm_attr = 0;
    if (!gemm_attr) {
        (void)hipFuncSetAttribute(reinterpret_cast<const void*>(&gemm256_kernel),
                                  hipFuncAttributeMaxDynamicSharedMemorySize, 114688);
        (void)hipFuncSetAttribute(reinterpret_cast<const void*>(&gemmko_kernel),
                                  hipFuncAttributeMaxDynamicSharedMemorySize, 98304);
        (void)hipFuncSetAttribute(reinterpret_cast<const void*>(&attn_kernel),
                                  hipFuncAttributeMaxDynamicSharedMemorySize, 36864);
        gemm_attr = 1;
    }

    convert_all_kernel<<<(CSEG4 + 255) / 256, 256, 0, stream>>>(x, Wq, Wk, Wv, Wo, xb, wqkv, wob);
    gemm256_kernel<<<dim3(QKVN / 192, TOKENS / 256), 512, 114688, stream>>>(xb, wqkv, qkvb, QKVN, EMBED);
    cache_prefix_kernel<<<256, 256, 0, stream>>>(ck, cv, sp, kh, vt8);
    rope_qk_kernel<<<TOKENS * 2560 / 256, 256, 0, stream>>>(qkvb, sp, qh, kh);
    vpack_kernel<<<1024, 256, 0, stream>>>(qkvb, sp, vt8);
    attn_kernel<<<1024, 256, 36864, stream>>>(qh, kh, vt8, sp, ctx);
    gemmko_kernel<<<dim3(EMBED / 256, TOKENS / 128), 512, 98304, stream>>>(ctx, wob, (float*)d_out, EMBED, EMBED);
}